// Round 3
// baseline (146.878 us; speedup 1.0000x reference)
//
#include <hip/hip_runtime.h>
#include <hip/hip_bf16.h>

// Embedding gather: out[tok, :] = w[ids[tok], :]
// ids: 8*2048 = 16384 int32 tokens; w: 50257 x 512 fp32; out: 16384 x 512 fp32.
// One float4 (16B) per thread; 128 float4 per row. Coalesced read & write.

#define TOKENS (8 * 2048)
#define UNITS 512
#define VEC_PER_ROW (UNITS / 4)  // 128 float4 per row

__global__ void embed_gather_kernel(const int* __restrict__ ids,
                                    const float4* __restrict__ w,
                                    float4* __restrict__ out) {
    int tid = blockIdx.x * blockDim.x + threadIdx.x;  // one float4 per thread
    // total = TOKENS * VEC_PER_ROW = 2,097,152 threads; grid sized exactly.
    int tok  = tid >> 7;        // tid / 128
    int elem = tid & 127;       // tid % 128
    int row = ids[tok];
    out[tid] = w[(long)row * VEC_PER_ROW + elem];
}

extern "C" void kernel_launch(void* const* d_in, const int* in_sizes, int n_in,
                              void* d_out, int out_size, void* d_ws, size_t ws_size,
                              hipStream_t stream) {
    const int* ids = (const int*)d_in[0];
    const float4* w = (const float4*)d_in[1];
    float4* out = (float4*)d_out;

    const int total_vec = TOKENS * VEC_PER_ROW;  // 2,097,152
    const int block = 256;
    const int grid = total_vec / block;          // 8192 blocks, exact
    embed_gather_kernel<<<grid, block, 0, stream>>>(ids, w, out);
}